// Round 5
// baseline (1474.385 us; speedup 1.0000x reference)
//
#include <hip/hip_runtime.h>

// Neighbor search: M=N=12288, DIM=3.
// d_out layout (float32, flat):
//   [0 .. M]                row_splits
//   [M+1 .. M+1+M*N)        mask (0.0 / 1.0)
//   [M+1+M*N .. +2*M*N)     weights (d2 if mask else 0)
//
// R6 = DIAGNOSTIC ROUND (deliberate, accepted regression).
// Four store-side theories are refuted (instr width R1/R2, 64B-line RMW R4,
// nt R4, write order R5): nbr is pinned at ~465us = 2.6 TB/s effective vs
// the 6.25 TB/s the poison fill demonstrates in the same window. We have
// never seen nbr's own counters (top-5 is saturated by ~20 fill dispatches
// at ~770us; nbr at ~465us never surfaces). This round runs the R4 main
// loop TWICE (pass 2 rewrites identical values; counts only in pass 0):
//  - nbr rises to ~900+us -> enters top-5 -> exposes FETCH/WRITE/VALUBusy/
//    Occupancy for the real kernel;
//  - timing discriminates: ~2x => write-throughput-bound (then FETCH tells
//    RMW-at-128B vs clean); <<2x => latency/issue-bound.
//
// Bit-exactness vs numpy/BLAS fp32 (unchanged):
//   sq = (x0*x0 + x1*x1) + x2*x2
//   dot = fma(q2,d2, fma(q1,d1, q0*d0))
//   d2  = (sq_q + sq_d) - 2*dot ; max(d2,0) ; mask = d2 <= r*r
// Pass 2 stores the same bytes to the same addresses from the same threads
// (program order per thread) -> final memory image identical to R4's.

#define BLK 256
#define ROWS 8
#define GTILE 512             // float4 column-groups per LDS tile
#define TWORDS (GTILE * 12)   // 6144 floats = 24 KB

typedef float floatx4 __attribute__((ext_vector_type(4)));

__global__ __launch_bounds__(BLK) void nbr_kernel(
    const float* __restrict__ data,
    const float* __restrict__ queries,
    const float* __restrict__ radius_p,
    float* __restrict__ out,
    int* __restrict__ counts,
    int N, long long mask_off, long long w_off, int cbase)
{
    __shared__ float4 tile4[GTILE * 3];
    float* tile = reinterpret_cast<float*>(tile4);
    __shared__ int lds_cnt[ROWS];

    const int tid = threadIdx.x;
    const int m0 = blockIdx.x * ROWS;

    const float r = radius_p[0];
    const float r2 = __fmul_rn(r, r);

    float q0[ROWS], q1[ROWS], q2[ROWS], sqq[ROWS];
#pragma unroll
    for (int rr = 0; rr < ROWS; ++rr) {
        q0[rr] = queries[3 * (m0 + rr) + 0];
        q1[rr] = queries[3 * (m0 + rr) + 1];
        q2[rr] = queries[3 * (m0 + rr) + 2];
        sqq[rr] = __fadd_rn(__fadd_rn(__fmul_rn(q0[rr], q0[rr]),
                                      __fmul_rn(q1[rr], q1[rr])),
                            __fmul_rn(q2[rr], q2[rr]));
    }

    float* mrow[ROWS];
    float* wrow[ROWS];
#pragma unroll
    for (int rr = 0; rr < ROWS; ++rr) {
        mrow[rr] = out + mask_off + (long long)(m0 + rr) * N;
        wrow[rr] = out + w_off    + (long long)(m0 + rr) * N;
    }

    int cnt[ROWS];
#pragma unroll
    for (int rr = 0; rr < ROWS; ++rr) cnt[rr] = 0;

    const int ng = (N - cbase) / 4;
    const int nspec = N - 4 * ng;  // cols 0..cbase-1 and cbase+4*ng..N-1

    for (int pass = 0; pass < 2; ++pass) {
        // Scalar prologue for the non-line-aligned columns.
        if (tid < nspec) {
            const int c = (tid < cbase) ? tid : (cbase + 4 * ng + (tid - cbase));
            const float d0  = data[3 * c + 0];
            const float d1  = data[3 * c + 1];
            const float d2e = data[3 * c + 2];
            const float sqd = __fadd_rn(
                __fadd_rn(__fmul_rn(d0, d0), __fmul_rn(d1, d1)),
                __fmul_rn(d2e, d2e));
#pragma unroll
            for (int rr = 0; rr < ROWS; ++rr) {
                const float dot = __fmaf_rn(q2[rr], d2e,
                                    __fmaf_rn(q1[rr], d1, __fmul_rn(q0[rr], d0)));
                float v = __fsub_rn(__fadd_rn(sqq[rr], sqd), __fmul_rn(2.0f, dot));
                v = fmaxf(v, 0.0f);
                const bool in = (v <= r2);
                mrow[rr][c] = in ? 1.0f : 0.0f;
                wrow[rr][c] = in ? v : 0.0f;
                if (pass == 0) cnt[rr] += in ? 1 : 0;
            }
        }

        // Main loop over column-group tiles.
        for (int g0 = 0; g0 < ng; g0 += GTILE) {
            const int ngt = min(GTILE, ng - g0);
            const long long W0 = 3LL * (cbase + 4LL * (long long)g0);
            const int lim = 12 * ngt;

            __syncthreads();  // previous tile's readers done before overwrite
            if (lim == TWORDS) {
#pragma unroll
                for (int k = 0; k < TWORDS / BLK; ++k)
                    tile[k * BLK + tid] = data[W0 + k * BLK + tid];
            } else {
                for (int w = tid; w < lim; w += BLK)
                    tile[w] = data[W0 + w];
            }
            __syncthreads();

#pragma unroll
            for (int k = 0; k < GTILE / BLK; ++k) {
                const int sl = k * BLK + tid;
                if (sl < ngt) {
                    const float4 A = tile4[3 * sl + 0];
                    const float4 B = tile4[3 * sl + 1];
                    const float4 C = tile4[3 * sl + 2];
                    // x0 y0 z0 x1 | y1 z1 x2 y2 | z2 x3 y3 z3
                    const float d0[4]  = {A.x, A.w, B.z, C.y};
                    const float d1[4]  = {A.y, B.x, B.w, C.z};
                    const float d2e[4] = {A.z, B.y, C.x, C.w};
                    float sqd[4];
#pragma unroll
                    for (int j = 0; j < 4; ++j)
                        sqd[j] = __fadd_rn(
                            __fadd_rn(__fmul_rn(d0[j], d0[j]),
                                      __fmul_rn(d1[j], d1[j])),
                            __fmul_rn(d2e[j], d2e[j]));

                    const int c = cbase + 4 * (g0 + sl);
#pragma unroll
                    for (int rr = 0; rr < ROWS; ++rr) {
                        float mv[4], wv[4];
                        int cc = 0;
#pragma unroll
                        for (int j = 0; j < 4; ++j) {
                            const float dot = __fmaf_rn(q2[rr], d2e[j],
                                                __fmaf_rn(q1[rr], d1[j],
                                                  __fmul_rn(q0[rr], d0[j])));
                            float v = __fsub_rn(__fadd_rn(sqq[rr], sqd[j]),
                                                __fmul_rn(2.0f, dot));
                            v = fmaxf(v, 0.0f);
                            const bool in = (v <= r2);
                            mv[j] = in ? 1.0f : 0.0f;
                            wv[j] = in ? v : 0.0f;
                            cc += in ? 1 : 0;
                        }
                        if (pass == 0) cnt[rr] += cc;
                        floatx4 mvec = {mv[0], mv[1], mv[2], mv[3]};
                        floatx4 wvec = {wv[0], wv[1], wv[2], wv[3]};
                        __builtin_nontemporal_store(
                            mvec, reinterpret_cast<floatx4*>(mrow[rr] + c));
                        __builtin_nontemporal_store(
                            wvec, reinterpret_cast<floatx4*>(wrow[rr] + c));
                    }
                }
            }
        }
    }

    // Per-row block count reduction: wave shuffle, then LDS across 4 waves.
    if (tid < ROWS) lds_cnt[tid] = 0;
    __syncthreads();
#pragma unroll
    for (int rr = 0; rr < ROWS; ++rr) {
        int c = cnt[rr];
        for (int off = 32; off > 0; off >>= 1) c += __shfl_down(c, off);
        if ((tid & 63) == 0) atomicAdd(&lds_cnt[rr], c);
    }
    __syncthreads();
    if (tid < ROWS) counts[m0 + tid] = lds_cnt[tid];
}

// Single-block exclusive scan of counts[M] -> row_splits[M+1] (as floats).
__global__ __launch_bounds__(256) void scan_kernel(
    const int* __restrict__ counts, float* __restrict__ out, int M)
{
    __shared__ int sums[256];
    const int t = threadIdx.x;
    const int CH = (M + 255) / 256;  // 48 for M=12288
    const int base = t * CH;

    int local[64];  // CH <= 64 assumed
    int s = 0;
    for (int i = 0; i < CH; ++i) {
        const int v = (base + i < M) ? counts[base + i] : 0;
        local[i] = v;
        s += v;
    }
    sums[t] = s;
    __syncthreads();
    for (int off = 1; off < 256; off <<= 1) {
        const int v = (t >= off) ? sums[t - off] : 0;
        __syncthreads();
        sums[t] += v;
        __syncthreads();
    }
    int prefix = sums[t] - s;  // exclusive prefix of this thread's chunk
    for (int i = 0; i < CH; ++i) {
        if (base + i < M) out[base + i] = (float)prefix;
        prefix += local[i];
    }
    if (t == 255) out[M] = (float)prefix;  // total
}

extern "C" void kernel_launch(void* const* d_in, const int* in_sizes, int n_in,
                              void* d_out, int out_size, void* d_ws, size_t ws_size,
                              hipStream_t stream) {
    const float* data    = (const float*)d_in[0];
    const float* queries = (const float*)d_in[1];
    const float* radius  = (const float*)d_in[2];

    const int N = in_sizes[0] / 3;  // 12288
    const int M = in_sizes[1] / 3;  // 12288

    float* out = (float*)d_out;
    int* counts = (int*)d_ws;

    const long long mask_off = (long long)M + 1;
    const long long w_off = mask_off + (long long)M * N;

    // First column c such that (mask_off + c) is 16-word (64B) aligned.
    const int cbase = (int)((16 - (mask_off & 15)) & 15);

    nbr_kernel<<<M / ROWS, BLK, 0, stream>>>(data, queries, radius, out, counts,
                                             N, mask_off, w_off, cbase);
    scan_kernel<<<1, 256, 0, stream>>>(counts, out, M);
}